// Round 3
// baseline (127.244 us; speedup 1.0000x reference)
//
#include <hip/hip_runtime.h>
#include <math.h>

// Density loss: B=8, N=2048, C=3, K=16 (includes self-distance 0).
// One wave per TWO query points (Q=2). Points staged SoA in LDS.
// Per lane: 4 candidates x 8 groups x 2 queries; only per-group-of-4 mins
// gm[8] are kept per query (no d[32] in registers).
// Selection per query (no prefix scans, no LDS scratch):
//   1) thr >= true d16 via interleaved ballot bisection on lane-mins.
//   2) each lane builds qmask of its qualifying groups (gm <= thr); wave
//      loops while any lane has bits (wave-max popcount ~2-3): pop own
//      lowest bit, re-read that group's 4 candidates from LDS, update
//      per-lane {qc, sum, top-3} in registers.
//   3) C via 3 ballots (per-lane qc<=3 or exact fallback); sum16 =
//      wave_sum(sq) - (C-16) largest, popped via wave-max rounds (E~2).
// Fallback (any lane qc>=4, ~1-2%/query): exact 16-round extraction with
// distance recompute from LDS.
// Each block reduces its 16 point-sums -> 1 partial. Kernel 2: 2048 -> MSE.

#define NPTS 2048
#define KSEL 16
#define WAVES_PER_BLOCK 8
#define BLOCK (WAVES_PER_BLOCK * 64)         // 512
#define PTS_PER_BLOCK (WAVES_PER_BLOCK * 2)  // 16
#define NGROUPS (NPTS / PTS_PER_BLOCK)       // 128
#define NBLOCKS (2 * 8 * NGROUPS)            // 2048

__device__ __forceinline__ float wave_sum_f(float v) {
  #pragma unroll
  for (int ofs = 32; ofs >= 1; ofs >>= 1) v += __shfl_xor(v, ofs);
  return v;
}

__device__ __forceinline__ float wave_max_f(float v) {
  #pragma unroll
  for (int ofs = 32; ofs >= 1; ofs >>= 1) v = fmaxf(v, __shfl_xor(v, ofs));
  return v;
}

__device__ __forceinline__ float dist2(float px, float py, float pz,
                                       float cx, float cy, float cz) {
  float dx = px - cx, dy = py - cy, dz = pz - cz;
  return fmaf(dz, dz, fmaf(dy, dy, dx * dx));
}

// Per-query selection from 8 register group-mins. Returns exact sum of the
// 16 smallest distances from this query to all 2048 staged points.
__device__ __forceinline__ float select_sum16(
    const float (&gm)[8], float thr, float px, float py, float pz, int lane,
    const float* xs, const float* ys, const float* zs) {
  // Per-lane mask of qualifying groups (group min <= thr).
  unsigned qmask = 0u;
  #pragma unroll
  for (int m = 0; m < 8; ++m) qmask |= (gm[m] <= thr) ? (1u << m) : 0u;

  // Wave-uniform loop over per-lane qualifying groups (max popcount ~2-3).
  int qc = 0;
  float sq = 0.f;
  float g0 = -INFINITY, g1 = -INFINITY, g2 = -INFINITY;
  while (__ballot(qmask != 0u) != 0ull) {
    const bool act = (qmask != 0u);
    const int m = __ffs(qmask) - 1;  // valid only if act
    qmask &= (qmask - 1u);
    const int o = act ? ((lane << 2) + (m << 8)) : 0;
    const float4 cx4 = *(const float4*)&xs[o];
    const float4 cy4 = *(const float4*)&ys[o];
    const float4 cz4 = *(const float4*)&zs[o];
    float dd;
    #pragma unroll
    for (int j = 0; j < 4; ++j) {
      const float cx = (j == 0) ? cx4.x : (j == 1) ? cx4.y : (j == 2) ? cx4.z : cx4.w;
      const float cy = (j == 0) ? cy4.x : (j == 1) ? cy4.y : (j == 2) ? cy4.z : cy4.w;
      const float cz = (j == 0) ? cz4.x : (j == 1) ? cz4.y : (j == 2) ? cz4.z : cz4.w;
      dd = dist2(px, py, pz, cx, cy, cz);
      const bool q = act && (dd <= thr);
      const float qd = q ? dd : -INFINITY;
      qc += q ? 1 : 0;
      sq += fmaxf(qd, 0.f);  // adds qualifying dd (>=0), else 0
      const bool c0 = qd > g0;
      const bool c1 = qd > g1;
      const float ng2 = c1 ? g1 : fmaxf(g2, qd);
      const float ng1 = c0 ? g0 : fmaxf(g1, qd);
      g2 = ng2;
      g1 = ng1;
      g0 = fmaxf(g0, qd);
    }
  }

  const unsigned long long anyb4 = __ballot(qc >= 4);
  if (anyb4 == 0ull) {
    // All qualifying values live in {g0,g1,g2} across the wave.
    const int C = __popcll(__ballot(qc >= 1)) + __popcll(__ballot(qc >= 2)) +
                  __popcll(__ballot(qc >= 3));  // C >= 16 guaranteed by thr
    const float S = wave_sum_f(sq);
    int extras = C - KSEL;  // E[extras] ~ 2
    float sub = 0.f;
    while (extras > 0) {
      const float M = wave_max_f(g0);  // finite: >16 values remain
      const unsigned long long sel = __ballot(g0 == M);
      const int leader = (int)__ffsll(sel) - 1;
      if (lane == leader) { g0 = g1; g1 = g2; g2 = -INFINITY; }
      sub += M;
      --extras;
    }
    return S - sub;
  }

  // Exact fallback (rare): 16 extraction rounds, recompute from LDS.
  float s = 0.f;
  unsigned consumed = 0u;
  #pragma unroll 1
  for (int r = 0; r < KSEL; ++r) {
    float bv = INFINITY;
    int bi = 0;
    #pragma unroll
    for (int m = 0; m < 8; ++m) {
      const int o = (lane << 2) + (m << 8);
      const float4 cx4 = *(const float4*)&xs[o];
      const float4 cy4 = *(const float4*)&ys[o];
      const float4 cz4 = *(const float4*)&zs[o];
      float dd;
      bool okb;
      dd = dist2(px, py, pz, cx4.x, cy4.x, cz4.x);
      okb = (((consumed >> ((m << 2) + 0)) & 1u) == 0u) && (dd < bv);
      bv = okb ? dd : bv; bi = okb ? ((m << 2) + 0) : bi;
      dd = dist2(px, py, pz, cx4.y, cy4.y, cz4.y);
      okb = (((consumed >> ((m << 2) + 1)) & 1u) == 0u) && (dd < bv);
      bv = okb ? dd : bv; bi = okb ? ((m << 2) + 1) : bi;
      dd = dist2(px, py, pz, cx4.z, cy4.z, cz4.z);
      okb = (((consumed >> ((m << 2) + 2)) & 1u) == 0u) && (dd < bv);
      bv = okb ? dd : bv; bi = okb ? ((m << 2) + 2) : bi;
      dd = dist2(px, py, pz, cx4.w, cy4.w, cz4.w);
      okb = (((consumed >> ((m << 2) + 3)) & 1u) == 0u) && (dd < bv);
      bv = okb ? dd : bv; bi = okb ? ((m << 2) + 3) : bi;
    }
    int bl = lane;
    #pragma unroll
    for (int ofs = 32; ofs >= 1; ofs >>= 1) {
      float ov = __shfl_xor(bv, ofs);
      int ol = __shfl_xor(bl, ofs);
      bool take = (ov < bv) || (ov == bv && ol < bl);
      bv = take ? ov : bv;
      bl = take ? ol : bl;
    }
    s += bv;
    if (lane == bl) consumed |= (1u << bi);
  }
  return s;
}

__global__ __launch_bounds__(BLOCK) void knn_sum16_kernel(
    const float* __restrict__ seed, const float* __restrict__ gt,
    float* __restrict__ out_part) {
  __shared__ float xs[NPTS];
  __shared__ float ys[NPTS];
  __shared__ float zs[NPTS];
  __shared__ float bsums[WAVES_PER_BLOCK];

  const int bid = blockIdx.x;        // 2048 blocks
  const int t = bid >> 10;           // tensor: 0=seed 1=gt
  const int b = (bid >> 7) & 7;      // batch
  const int g = bid & 127;           // point-group within batch
  const float* base = (t == 0 ? seed : gt) + b * NPTS * 3;

  const int tid = threadIdx.x;

  // Stage SoA: thread tid handles points 4*tid..4*tid+3 (12 floats).
  {
    const float4* src = (const float4*)base;
    float4 f0 = src[3 * tid + 0];
    float4 f1 = src[3 * tid + 1];
    float4 f2 = src[3 * tid + 2];
    *(float4*)&xs[4 * tid] = make_float4(f0.x, f0.w, f1.z, f2.y);
    *(float4*)&ys[4 * tid] = make_float4(f0.y, f1.x, f1.w, f2.z);
    *(float4*)&zs[4 * tid] = make_float4(f0.z, f1.y, f2.x, f2.w);
  }
  __syncthreads();

  const int wave = tid >> 6;
  const int lane = tid & 63;
  const int iA = g * PTS_PER_BLOCK + wave * 2;  // query point A
  const int iB = iA + 1;                        // query point B
  const float pax = xs[iA], pay = ys[iA], paz = zs[iA];
  const float pbx = xs[iB], pby = ys[iB], pbz = zs[iB];

  // Distance pass: candidate index = 4*lane + j + 256*m. Keep group mins.
  float gmA[8], gmB[8];
  #pragma unroll
  for (int m = 0; m < 8; ++m) {
    const int o = (lane << 2) + (m << 8);
    const float4 cx4 = *(const float4*)&xs[o];
    const float4 cy4 = *(const float4*)&ys[o];
    const float4 cz4 = *(const float4*)&zs[o];
    float a0 = dist2(pax, pay, paz, cx4.x, cy4.x, cz4.x);
    float a1 = dist2(pax, pay, paz, cx4.y, cy4.y, cz4.y);
    float a2 = dist2(pax, pay, paz, cx4.z, cy4.z, cz4.z);
    float a3 = dist2(pax, pay, paz, cx4.w, cy4.w, cz4.w);
    gmA[m] = fminf(fminf(a0, a1), fminf(a2, a3));
    float b0 = dist2(pbx, pby, pbz, cx4.x, cy4.x, cz4.x);
    float b1 = dist2(pbx, pby, pbz, cx4.y, cy4.y, cz4.y);
    float b2 = dist2(pbx, pby, pbz, cx4.z, cy4.z, cz4.z);
    float b3 = dist2(pbx, pby, pbz, cx4.w, cy4.w, cz4.w);
    gmB[m] = fminf(fminf(b0, b1), fminf(b2, b3));
  }
  float lminA = gmA[0], lminB = gmB[0];
  #pragma unroll
  for (int m = 1; m < 8; ++m) {
    lminA = fminf(lminA, gmA[m]);
    lminB = fminf(lminB, gmB[m]);
  }

  // Interleaved threshold bisection (16 rounds): thr >= 16th-smallest
  // lane-min >= true d16. Nonneg floats are uint-order-isomorphic.
  const unsigned uA = __float_as_uint(lminA);
  const unsigned uB = __float_as_uint(lminB);
  unsigned loA = 0u, hiA = 0x7F800000u, loB = 0u, hiB = 0x7F800000u;
  #pragma unroll
  for (int r = 0; r < 16; ++r) {
    const unsigned midA = (loA + hiA) >> 1;
    const unsigned midB = (loB + hiB) >> 1;
    const int cA = __popcll(__ballot(uA <= midA));
    const int cB = __popcll(__ballot(uB <= midB));
    const bool gA = cA >= KSEL;
    const bool gB = cB >= KSEL;
    hiA = gA ? midA : hiA;
    loA = gA ? loA : midA;
    hiB = gB ? midB : hiB;
    loB = gB ? loB : midB;
  }
  const float thrA = __uint_as_float(hiA);
  const float thrB = __uint_as_float(hiB);

  const float sumA = select_sum16(gmA, thrA, pax, pay, paz, lane, xs, ys, zs);
  const float sumB = select_sum16(gmB, thrB, pbx, pby, pbz, lane, xs, ys, zs);

  if (lane == 0) bsums[wave] = sumA + sumB;
  __syncthreads();
  if (tid == 0) {
    float s = 0.f;
    #pragma unroll
    for (int w = 0; w < WAVES_PER_BLOCK; ++w) s += bsums[w];
    out_part[bid] = s;
  }
}

__global__ __launch_bounds__(1024) void final_reduce_kernel(
    const float* __restrict__ parts, float* __restrict__ out) {
  __shared__ float partial[16];
  const int tid = threadIdx.x;
  const int wave = tid >> 6;
  const int lane = tid & 63;
  // wave w reduces segment (t,b) = w: 128 block partials.
  float s = parts[wave * NGROUPS + lane] + parts[wave * NGROUPS + 64 + lane];
  #pragma unroll
  for (int ofs = 32; ofs >= 1; ofs >>= 1) s += __shfl_xor(s, ofs);
  if (lane == 0) partial[wave] = s;
  __syncthreads();
  if (tid == 0) {
    const float scale = 1.f / (2048.f * 16.f);  // mean over points, mean over k
    float acc = 0.f;
    #pragma unroll
    for (int bb = 0; bb < 8; ++bb) {
      float diff = (partial[bb] - partial[8 + bb]) * scale;
      acc += diff * diff;
    }
    out[0] = acc * 0.125f;
  }
}

extern "C" void kernel_launch(void* const* d_in, const int* in_sizes, int n_in,
                              void* d_out, int out_size, void* d_ws, size_t ws_size,
                              hipStream_t stream) {
  const float* seed = (const float*)d_in[0];
  const float* gt = (const float*)d_in[1];
  float* out = (float*)d_out;
  float* ws = (float*)d_ws;  // needs 2048 floats = 8 KB

  knn_sum16_kernel<<<NBLOCKS, BLOCK, 0, stream>>>(seed, gt, ws);
  final_reduce_kernel<<<1, 1024, 0, stream>>>(ws, out);
}

// Round 5
// 93.527 us; speedup vs baseline: 1.3605x; 1.3605x over previous
//
#include <hip/hip_runtime.h>
#include <math.h>

// Density loss: B=8, N=2048, C=3, K=16 (includes self-distance 0).
// One wave per TWO query points (Q=2). Points staged SoA in LDS.
// Structure = round-2 skeleton (passed, 42.7us) + intra-wave improvements:
//   1) distance pass keeps per-group-of-4 mins gm[8] per query.
//   2) thr >= true d16 via interleaved ballot bisection on lane-mins with
//      early-exit acceptance band count in [16,24] (E ~8-10 rounds).
//   3) group compaction via ballot+mbcnt bit-planes (no shfl_up chains);
//      redistribute 1 group/lane, recompute its 4 distances. Values > thr
//      are kept (harmless: the 16 smallest are all <= thr and present).
//   4) exact sum of 16 smallest via interleaved A/B early-exit bit bisection
//      over the <=4 register values/lane (4 ballots/query/round, E ~12
//      rounds; exit when count==16 -> sum directly; else exact-t* formula
//      after <=32 rounds). Register-only, wave-uniform trip counts.
// Fallback (group-scratch overflow, ~never): exact 16-round extraction.
// Kernel 2 (separate launch = safe cross-block handoff): 2048 partials -> MSE.

#define NPTS 2048
#define KSEL 16
#define WAVES_PER_BLOCK 8
#define BLOCK (WAVES_PER_BLOCK * 64)         // 512
#define PTS_PER_BLOCK (WAVES_PER_BLOCK * 2)  // 16
#define NGROUPS (NPTS / PTS_PER_BLOCK)       // 128
#define NBLOCKS (2 * 8 * NGROUPS)            // 2048

__device__ __forceinline__ int mbcnt64(unsigned long long m) {
  // popcount of m restricted to lanes strictly below this lane.
  return __builtin_amdgcn_mbcnt_hi(
      (unsigned)(m >> 32), __builtin_amdgcn_mbcnt_lo((unsigned)m, 0u));
}

__device__ __forceinline__ float dist2(float px, float py, float pz,
                                       float cx, float cy, float cz) {
  float dx = px - cx, dy = py - cy, dz = pz - cz;
  return fmaf(dz, dz, fmaf(dy, dy, dx * dx));
}

// Redistribute qualifying groups (gm <= thr) one-per-lane via scrI; each
// active lane recomputes its group's 4 distances (bitwise-identical fmaf).
// Inactive lanes get INF. ok=false (wave-uniform) iff >64 qualifying groups.
__device__ __forceinline__ void gather_candidates(
    const float (&gm)[8], float thr, float px, float py, float pz, int lane,
    const float* xs, const float* ys, const float* zs, int* scrI, bool& ok,
    float& d0, float& d1, float& d2, float& d3) {
  unsigned qmask = 0u;
  int qg = 0;
  #pragma unroll
  for (int m = 0; m < 8; ++m) {
    const bool q = gm[m] <= thr;
    qmask |= q ? (1u << m) : 0u;
    qg += q ? 1 : 0;
  }
  // Exclusive prefix + total of qg (0..8) via bit-plane ballots.
  const unsigned long long b0 = __ballot((qg & 1) != 0);
  const unsigned long long b1 = __ballot((qg & 2) != 0);
  const unsigned long long b2 = __ballot((qg & 4) != 0);
  const unsigned long long b3 = __ballot((qg & 8) != 0);
  const int pre =
      mbcnt64(b0) + 2 * mbcnt64(b1) + 4 * mbcnt64(b2) + 8 * mbcnt64(b3);
  const int tot = __popcll(b0) + 2 * __popcll(b1) + 4 * __popcll(b2) +
                  8 * __popcll(b3);
  ok = (tot <= 64);
  if (ok) {
    int pos = pre;
    #pragma unroll
    for (int m = 0; m < 8; ++m) {
      if ((qmask >> m) & 1u) {
        scrI[pos] = (lane << 3) | m;
        ++pos;
      }
    }
  }
  d0 = INFINITY; d1 = INFINITY; d2 = INFINITY; d3 = INFINITY;
  if (ok && lane < tot) {
    const int id = scrI[lane];
    const int o = ((id >> 3) << 2) + ((id & 7) << 8);
    const float4 cx4 = *(const float4*)&xs[o];
    const float4 cy4 = *(const float4*)&ys[o];
    const float4 cz4 = *(const float4*)&zs[o];
    d0 = dist2(px, py, pz, cx4.x, cy4.x, cz4.x);
    d1 = dist2(px, py, pz, cx4.y, cy4.y, cz4.y);
    d2 = dist2(px, py, pz, cx4.z, cy4.z, cz4.z);
    d3 = dist2(px, py, pz, cx4.w, cy4.w, cz4.w);
  }
}

// Exact fallback (~never): 16 extraction rounds, recompute from LDS.
__device__ float fallback_sum16(float px, float py, float pz, int lane,
                                const float* xs, const float* ys,
                                const float* zs) {
  float s = 0.f;
  unsigned consumed = 0u;
  #pragma unroll 1
  for (int r = 0; r < KSEL; ++r) {
    float bv = INFINITY;
    int bi = 0;
    #pragma unroll
    for (int m = 0; m < 8; ++m) {
      const int o = (lane << 2) + (m << 8);
      const float4 cx4 = *(const float4*)&xs[o];
      const float4 cy4 = *(const float4*)&ys[o];
      const float4 cz4 = *(const float4*)&zs[o];
      float dd;
      bool okb;
      dd = dist2(px, py, pz, cx4.x, cy4.x, cz4.x);
      okb = (((consumed >> ((m << 2) + 0)) & 1u) == 0u) && (dd < bv);
      bv = okb ? dd : bv; bi = okb ? ((m << 2) + 0) : bi;
      dd = dist2(px, py, pz, cx4.y, cy4.y, cz4.y);
      okb = (((consumed >> ((m << 2) + 1)) & 1u) == 0u) && (dd < bv);
      bv = okb ? dd : bv; bi = okb ? ((m << 2) + 1) : bi;
      dd = dist2(px, py, pz, cx4.z, cy4.z, cz4.z);
      okb = (((consumed >> ((m << 2) + 2)) & 1u) == 0u) && (dd < bv);
      bv = okb ? dd : bv; bi = okb ? ((m << 2) + 2) : bi;
      dd = dist2(px, py, pz, cx4.w, cy4.w, cz4.w);
      okb = (((consumed >> ((m << 2) + 3)) & 1u) == 0u) && (dd < bv);
      bv = okb ? dd : bv; bi = okb ? ((m << 2) + 3) : bi;
    }
    int bl = lane;
    #pragma unroll
    for (int ofs = 32; ofs >= 1; ofs >>= 1) {
      float ov = __shfl_xor(bv, ofs);
      int ol = __shfl_xor(bl, ofs);
      bool take = (ov < bv) || (ov == bv && ol < bl);
      bv = take ? ov : bv;
      bl = take ? ol : bl;
    }
    s += bv;
    if (lane == bl) consumed |= (1u << bi);
  }
  return s;
}

__global__ __launch_bounds__(BLOCK) void knn_sum16_kernel(
    const float* __restrict__ seed, const float* __restrict__ gt,
    float* __restrict__ out_part) {
  __shared__ float xs[NPTS];
  __shared__ float ys[NPTS];
  __shared__ float zs[NPTS];
  __shared__ int scrI[WAVES_PER_BLOCK][2][64];
  __shared__ float bsums[WAVES_PER_BLOCK];

  const int bid = blockIdx.x;        // 2048 blocks
  const int t = bid >> 10;           // tensor: 0=seed 1=gt
  const int b = (bid >> 7) & 7;      // batch
  const int g = bid & 127;           // point-group within batch
  const float* base = (t == 0 ? seed : gt) + b * NPTS * 3;

  const int tid = threadIdx.x;

  // Stage SoA: thread tid handles points 4*tid..4*tid+3 (12 floats).
  {
    const float4* src = (const float4*)base;
    float4 f0 = src[3 * tid + 0];
    float4 f1 = src[3 * tid + 1];
    float4 f2 = src[3 * tid + 2];
    *(float4*)&xs[4 * tid] = make_float4(f0.x, f0.w, f1.z, f2.y);
    *(float4*)&ys[4 * tid] = make_float4(f0.y, f1.x, f1.w, f2.z);
    *(float4*)&zs[4 * tid] = make_float4(f0.z, f1.y, f2.x, f2.w);
  }
  __syncthreads();

  const int wave = tid >> 6;
  const int lane = tid & 63;
  const int iA = g * PTS_PER_BLOCK + wave * 2;  // query point A
  const int iB = iA + 1;                        // query point B
  const float pax = xs[iA], pay = ys[iA], paz = zs[iA];
  const float pbx = xs[iB], pby = ys[iB], pbz = zs[iB];

  // Distance pass: candidate index = 4*lane + j + 256*m. Keep group mins.
  float gmA[8], gmB[8];
  #pragma unroll
  for (int m = 0; m < 8; ++m) {
    const int o = (lane << 2) + (m << 8);
    const float4 cx4 = *(const float4*)&xs[o];
    const float4 cy4 = *(const float4*)&ys[o];
    const float4 cz4 = *(const float4*)&zs[o];
    float a0 = dist2(pax, pay, paz, cx4.x, cy4.x, cz4.x);
    float a1 = dist2(pax, pay, paz, cx4.y, cy4.y, cz4.y);
    float a2 = dist2(pax, pay, paz, cx4.z, cy4.z, cz4.z);
    float a3 = dist2(pax, pay, paz, cx4.w, cy4.w, cz4.w);
    gmA[m] = fminf(fminf(a0, a1), fminf(a2, a3));
    float b0 = dist2(pbx, pby, pbz, cx4.x, cy4.x, cz4.x);
    float b1 = dist2(pbx, pby, pbz, cx4.y, cy4.y, cz4.y);
    float b2 = dist2(pbx, pby, pbz, cx4.z, cy4.z, cz4.z);
    float b3 = dist2(pbx, pby, pbz, cx4.w, cy4.w, cz4.w);
    gmB[m] = fminf(fminf(b0, b1), fminf(b2, b3));
  }
  float lminA = gmA[0], lminB = gmB[0];
  #pragma unroll
  for (int m = 1; m < 8; ++m) {
    lminA = fminf(lminA, gmA[m]);
    lminB = fminf(lminB, gmB[m]);
  }

  // Threshold bisection on lane-mins (uint-order-isomorphic for nonneg
  // floats), interleaved A/B, early-exit when count lands in [16,24].
  // Invariant: count(lane-min <= hi) >= 16  =>  thr >= true d16.
  const unsigned uA = __float_as_uint(lminA);
  const unsigned uB = __float_as_uint(lminB);
  unsigned loA = 0u, hiA = 0x7F800000u, loB = 0u, hiB = 0x7F800000u;
  bool thA = false, thB = false;
  #pragma unroll 1
  for (int r = 0; r < 16; ++r) {
    if (thA && thB) break;  // wave-uniform
    const unsigned midA = (loA + hiA) >> 1;
    const unsigned midB = (loB + hiB) >> 1;
    const int cA = __popcll(__ballot(uA <= midA));
    const int cB = __popcll(__ballot(uB <= midB));
    if (!thA) {
      const bool gA = cA >= KSEL;
      hiA = gA ? midA : hiA;
      loA = gA ? loA : midA;
      thA = (cA >= KSEL) && (cA <= 24);
    }
    if (!thB) {
      const bool gB = cB >= KSEL;
      hiB = gB ? midB : hiB;
      loB = gB ? loB : midB;
      thB = (cB >= KSEL) && (cB <= 24);
    }
  }
  const float thrA = __uint_as_float(hiA);
  const float thrB = __uint_as_float(hiB);

  // Gather candidates: <=4 register distances per lane per query. Candidate
  // multiset contains every distance <= thr (>=16 of them), so its 16
  // smallest equal the true 16 smallest.
  bool okA, okB;
  float a0, a1, a2, a3, b0, b1, b2, b3;
  gather_candidates(gmA, thrA, pax, pay, paz, lane, xs, ys, zs,
                    &scrI[wave][0][0], okA, a0, a1, a2, a3);
  gather_candidates(gmB, thrB, pbx, pby, pbz, lane, xs, ys, zs,
                    &scrI[wave][1][0], okB, b0, b1, b2, b3);

  // Exact 16-smallest sum via interleaved early-exit bit bisection on
  // w = bits(d)+1 (monotone; w>=1; INF -> 0x7F800001 = initial hi).
  // Invariants: count(w <= hi) >= 16 > count(w <= lo). Exit when count==16
  // (sum values with w <= mid directly); else after <=32 rounds hi = lo+1,
  // t* = value(hi-1), sum = sum(w<=lo) + (16 - count(w<=lo)) * t*.
  const unsigned wa0 = __float_as_uint(a0) + 1u, wa1 = __float_as_uint(a1) + 1u;
  const unsigned wa2 = __float_as_uint(a2) + 1u, wa3 = __float_as_uint(a3) + 1u;
  const unsigned wb0 = __float_as_uint(b0) + 1u, wb1 = __float_as_uint(b1) + 1u;
  const unsigned wb2 = __float_as_uint(b2) + 1u, wb3 = __float_as_uint(b3) + 1u;
  unsigned eloA = 0u, ehiA = 0x7F800001u, eloB = 0u, ehiB = 0x7F800001u;
  bool hA = false, hB = false;
  unsigned sA = 0u, sB = 0u;
  #pragma unroll 1
  for (int r = 0; r < 32; ++r) {
    const bool needA = okA && !hA;
    const bool needB = okB && !hB;
    if (!(needA || needB)) break;  // wave-uniform
    const unsigned midA = (eloA + ehiA) >> 1;
    const unsigned midB = (eloB + ehiB) >> 1;
    const int cA = __popcll(__ballot(wa0 <= midA)) +
                   __popcll(__ballot(wa1 <= midA)) +
                   __popcll(__ballot(wa2 <= midA)) +
                   __popcll(__ballot(wa3 <= midA));
    const int cB = __popcll(__ballot(wb0 <= midB)) +
                   __popcll(__ballot(wb1 <= midB)) +
                   __popcll(__ballot(wb2 <= midB)) +
                   __popcll(__ballot(wb3 <= midB));
    if (needA) {
      if (cA >= KSEL) ehiA = midA; else eloA = midA;
      if (cA == KSEL) { hA = true; sA = midA; }
    }
    if (needB) {
      if (cB >= KSEL) ehiB = midB; else eloB = midB;
      if (cB == KSEL) { hB = true; sB = midB; }
    }
  }
  float extraA = 0.f, extraB = 0.f;
  if (okA && !hA) {
    sA = eloA;
    const int nlo = __popcll(__ballot(wa0 <= eloA)) +
                    __popcll(__ballot(wa1 <= eloA)) +
                    __popcll(__ballot(wa2 <= eloA)) +
                    __popcll(__ballot(wa3 <= eloA));
    extraA = (float)(KSEL - nlo) * __uint_as_float(ehiA - 1u);
  }
  if (okB && !hB) {
    sB = eloB;
    const int nlo = __popcll(__ballot(wb0 <= eloB)) +
                    __popcll(__ballot(wb1 <= eloB)) +
                    __popcll(__ballot(wb2 <= eloB)) +
                    __popcll(__ballot(wb3 <= eloB));
    extraB = (float)(KSEL - nlo) * __uint_as_float(ehiB - 1u);
  }
  float ca = 0.f, cb = 0.f;
  if (okA) {
    ca = ((wa0 <= sA) ? a0 : 0.f) + ((wa1 <= sA) ? a1 : 0.f) +
         ((wa2 <= sA) ? a2 : 0.f) + ((wa3 <= sA) ? a3 : 0.f);
  }
  if (okB) {
    cb = ((wb0 <= sB) ? b0 : 0.f) + ((wb1 <= sB) ? b1 : 0.f) +
         ((wb2 <= sB) ? b2 : 0.f) + ((wb3 <= sB) ? b3 : 0.f);
  }
  #pragma unroll
  for (int ofs = 32; ofs >= 1; ofs >>= 1) {
    ca += __shfl_xor(ca, ofs);
    cb += __shfl_xor(cb, ofs);
  }
  float sumA = ca + extraA;
  float sumB = cb + extraB;
  if (!okA) sumA = fallback_sum16(pax, pay, paz, lane, xs, ys, zs);
  if (!okB) sumB = fallback_sum16(pbx, pby, pbz, lane, xs, ys, zs);

  if (lane == 0) bsums[wave] = sumA + sumB;
  __syncthreads();
  if (tid == 0) {
    float s = 0.f;
    #pragma unroll
    for (int w = 0; w < WAVES_PER_BLOCK; ++w) s += bsums[w];
    out_part[bid] = s;
  }
}

__global__ __launch_bounds__(1024) void final_reduce_kernel(
    const float* __restrict__ parts, float* __restrict__ out) {
  __shared__ float partial[16];
  const int tid = threadIdx.x;
  const int wave = tid >> 6;
  const int lane = tid & 63;
  // wave w reduces segment (t,b) = w: 128 block partials.
  float s = parts[wave * NGROUPS + lane] + parts[wave * NGROUPS + 64 + lane];
  #pragma unroll
  for (int ofs = 32; ofs >= 1; ofs >>= 1) s += __shfl_xor(s, ofs);
  if (lane == 0) partial[wave] = s;
  __syncthreads();
  if (tid == 0) {
    const float scale = 1.f / (2048.f * 16.f);  // mean over points, mean over k
    float acc = 0.f;
    #pragma unroll
    for (int bb = 0; bb < 8; ++bb) {
      float diff = (partial[bb] - partial[8 + bb]) * scale;
      acc += diff * diff;
    }
    out[0] = acc * 0.125f;
  }
}

extern "C" void kernel_launch(void* const* d_in, const int* in_sizes, int n_in,
                              void* d_out, int out_size, void* d_ws, size_t ws_size,
                              hipStream_t stream) {
  const float* seed = (const float*)d_in[0];
  const float* gt = (const float*)d_in[1];
  float* out = (float*)d_out;
  float* ws = (float*)d_ws;  // needs 2048 floats = 8 KB

  knn_sum16_kernel<<<NBLOCKS, BLOCK, 0, stream>>>(seed, gt, ws);
  final_reduce_kernel<<<1, 1024, 0, stream>>>(ws, out);
}